// Round 13
// baseline (174.129 us; speedup 1.0000x reference)
//
#include <hip/hip_runtime.h>
#include <hip/hip_bf16.h>

typedef __attribute__((ext_vector_type(8))) short short8;
typedef __attribute__((ext_vector_type(8))) __bf16 bf16x8;
typedef __attribute__((ext_vector_type(4))) float f32x4;

static __device__ __forceinline__ float bflo(unsigned u){ return __uint_as_float(u << 16); }
static __device__ __forceinline__ float bfhi(unsigned u){ return __uint_as_float(u & 0xffff0000u); }
static __device__ __forceinline__ unsigned short f2bf(float f){
  unsigned u = __float_as_uint(f);
  unsigned r = u + 0x7fffu + ((u >> 16) & 1u);
  return (unsigned short)(r >> 16);
}

// ---- fp8 e4m3 decode (HW via builtin; SW fallback) ----
#if __has_builtin(__builtin_amdgcn_cvt_pk_f32_fp8)
static __device__ __forceinline__ float4 e4m3x4_to_f32(unsigned u){
  auto lo = __builtin_amdgcn_cvt_pk_f32_fp8((int)u, false);
  auto hi = __builtin_amdgcn_cvt_pk_f32_fp8((int)u, true);
  return make_float4(lo[0], lo[1], hi[0], hi[1]);
}
#else
static __device__ __forceinline__ float e4m3_1(unsigned b){
  unsigned s = b >> 7, e = (b >> 3) & 15, m = b & 7;
  float v = e ? ldexpf((float)(8 + m) * 0.125f, (int)e - 7) : ldexpf((float)m * 0.125f, -6);
  return s ? -v : v;
}
static __device__ __forceinline__ float4 e4m3x4_to_f32(unsigned u){
  return make_float4(e4m3_1(u & 255), e4m3_1((u >> 8) & 255), e4m3_1((u >> 16) & 255), e4m3_1(u >> 24));
}
#endif

// ---- fp4 e2m1 (values scaled x4 at encode; 0.25 folded into dinv at decode) ----
// encode f32 -> nibble (RTN on grid {0,.5,1,1.5,2,3,4,6})
static __device__ __forceinline__ unsigned enc_fp4(float v){
  float a = fabsf(v) * 4.0f;
  unsigned n = a < 0.25f ? 0u : a < 0.75f ? 1u : a < 1.25f ? 2u : a < 1.75f ? 3u
             : a < 2.5f  ? 4u : a < 3.5f  ? 5u : a < 5.0f  ? 6u : 7u;
  return n | (v < 0.f ? 8u : 0u);
}

// decode 8 fp4 (one dword) and accumulate; acc[j] = feature (gl*8 + j)
// nibble j of the dword = feature j. e2m1 abs values map EXACTLY onto e4m3 bytes:
// {0,.5,1,1.5,2,3,4,6} -> {00,30,38,3C,40,44,48,4C}; sign nibble-bit3 -> byte-bit7.
static __device__ __forceinline__ void add8_fp4(float* acc, unsigned u){
  unsigned b0 = u & 0x0F0F0F0Fu;          // nibbles 0,2,4,6
  unsigned b1 = (u >> 4) & 0x0F0F0F0Fu;   // nibbles 1,3,5,7
  const unsigned Tlo = 0x3C383000u;       // LUT idx 0..3
  const unsigned Thi = 0x4C484440u;       // LUT idx 4..7
  unsigned f0 = __builtin_amdgcn_perm(Thi, Tlo, b0 & 0x07070707u) | ((b0 & 0x08080808u) << 4);
  unsigned f1 = __builtin_amdgcn_perm(Thi, Tlo, b1 & 0x07070707u) | ((b1 & 0x08080808u) << 4);
  float4 d0 = e4m3x4_to_f32(f0);
  float4 d1 = e4m3x4_to_f32(f1);
  acc[0] += d0.x; acc[2] += d0.y; acc[4] += d0.z; acc[6] += d0.w;
  acc[1] += d1.x; acc[3] += d1.y; acc[5] += d1.z; acc[7] += d1.w;
}

#define NBMAX  1024
#define PART_C 4096
#define STCAP  4096
#define BCAP   6144   // per-bucket ebuf capacity (mean 2046, +90 sigma)

// ---------------- bucket pipeline (unchanged from round 12) ----------------

__global__ __launch_bounds__(1024) void k_part(const int* __restrict__ src, const int* __restrict__ dst,
    int* __restrict__ bpos, unsigned* __restrict__ ebuf, int E, int NB)
{
  __shared__ int hist[NBMAX + 1];
  __shared__ int hist2[NBMAX];
  __shared__ int gbase[NBMAX];
  __shared__ int sc[1024];
  __shared__ unsigned staged[PART_C];
  __shared__ unsigned short sbkt[PART_C];

  const int t = threadIdx.x;
  const int base = blockIdx.x * PART_C;

  for (int i = t; i < NBMAX; i += 1024){ hist[i] = 0; hist2[i] = 0; }
  __syncthreads();

  unsigned up[4];
  int bb[4];
  #pragma unroll
  for (int j = 0; j < 4; j++){
    int e = base + j * 1024 + t;
    if (e < E){
      int s = src[e], d = dst[e];
      bb[j] = d >> 7;
      up[j] = ((unsigned)s << 7) | (unsigned)(d & 127);
      atomicAdd(&hist[bb[j]], 1);
    } else bb[j] = -1;
  }
  __syncthreads();

  int v = (t < NB) ? hist[t] : 0;
  sc[t] = v; __syncthreads();
  for (int off = 1; off < 1024; off <<= 1){
    int u = (t >= off) ? sc[t - off] : 0;
    __syncthreads();
    sc[t] += u;
    __syncthreads();
  }
  int incl = sc[t];
  if (t < NB) hist[t] = incl - v;
  if (t == NB - 1) hist[NB] = incl;
  if (t < NB && v > 0) gbase[t] = t * BCAP + atomicAdd(&bpos[t], v);
  __syncthreads();

  #pragma unroll
  for (int j = 0; j < 4; j++){
    if (bb[j] >= 0){
      int r = atomicAdd(&hist2[bb[j]], 1);
      int p = hist[bb[j]] + r;
      staged[p] = up[j];
      sbkt[p] = (unsigned short)bb[j];
    }
  }
  __syncthreads();

  int total = hist[NB];
  for (int i = t; i < total; i += 1024){
    int b = sbkt[i];
    ebuf[gbase[b] + (i - hist[b])] = staged[i];
  }
}

__global__ __launch_bounds__(1024) void k_cscan(const int* __restrict__ cnts, int* __restrict__ bstart,
    int* __restrict__ rowptr, int NB, int N, int E){
  __shared__ int sc[1024];
  const int t = threadIdx.x;
  int v = (t < NB) ? cnts[t] : 0;
  sc[t] = v; __syncthreads();
  for (int off = 1; off < 1024; off <<= 1){
    int u = (t >= off) ? sc[t - off] : 0;
    __syncthreads();
    sc[t] += u;
    __syncthreads();
  }
  if (t < NB) bstart[t] = sc[t] - v;
  if (t == 0){ bstart[NB] = E; rowptr[N] = E; }
}

__global__ __launch_bounds__(256) void k_bsort(const unsigned* __restrict__ ebuf, const int* __restrict__ cnts,
    const int* __restrict__ bstart, int* __restrict__ rowptr, int* __restrict__ colv,
    float* __restrict__ dinv, int n)
{
  __shared__ int cl[128];
  __shared__ int sc2[256];
  __shared__ unsigned stg[STCAP];

  const int t = threadIdx.x;
  const int b = blockIdx.x;
  const int r0 = b << 7;
  const int rbeg = b * BCAP;
  const int total = cnts[b];
  const int wbeg = bstart[b];

  if (t < 128) cl[t] = 0;
  __syncthreads();
  for (int i = t; i < total; i += 256) atomicAdd(&cl[ebuf[rbeg + i] & 127u], 1);
  __syncthreads();

  int v = (t < 128) ? cl[t] : 0;
  sc2[t] = v; __syncthreads();
  for (int off = 1; off < 256; off <<= 1){
    int u = (t >= off) ? sc2[t - off] : 0;
    __syncthreads();
    sc2[t] += u;
    __syncthreads();
  }
  int excl = sc2[t] - v;
  if (t < 128){
    int node = r0 + t;
    if (node < n){
      rowptr[node] = wbeg + excl;
      dinv[node]   = rsqrtf((float)(v + 1));
    }
    cl[t] = excl;
  }
  __syncthreads();

  if (total <= STCAP){
    for (int i = t; i < total; i += 256){
      unsigned u = ebuf[rbeg + i];
      int p = atomicAdd(&cl[u & 127u], 1);
      stg[p] = u >> 7;
    }
    __syncthreads();
    for (int i = t; i < total; i += 256) colv[wbeg + i] = (int)stg[i];
  } else {
    for (int i = t; i < total; i += 256){
      unsigned u = ebuf[rbeg + i];
      int p = atomicAdd(&cl[u & 127u], 1);
      colv[wbeg + p] = (int)(u >> 7);
    }
  }
}

// ---------------- MFMA GEMM: G4[i,:] = fp4( dinv[i] * (A[i,:] @ W) ), scale x4 ----------------

template<bool AF32>
__global__ __launch_bounds__(512) void k_gemm_mfma(const void* __restrict__ Ain, const float* __restrict__ W,
    const float* __restrict__ dinv, unsigned char* __restrict__ G4, int n)
{
  __shared__ unsigned short At[128 * 136];
  __shared__ float dl[128];

  const int t = threadIdx.x;
  const int rowBase = blockIdx.x * 128;
  const int w  = t >> 6;
  const int l  = t & 63;
  const int ln = l & 15;
  const int lg = l >> 4;

  if (t < 128){
    int gr = rowBase + t;
    dl[t] = (gr < n) ? dinv[gr] : 0.f;
  }

  #pragma unroll
  for (int i = 0; i < 4; i++){
    int flat = i * 4096 + t * 8;
    int r = flat >> 7, c = flat & 127;
    int gr = rowBase + r;
    unsigned short tmp[8];
    if constexpr (AF32){
      const float* A = (const float*)Ain;
      float4 v0 = make_float4(0.f,0.f,0.f,0.f), v1 = v0;
      if (gr < n){
        v0 = *(const float4*)(A + (size_t)gr * 128 + c);
        v1 = *(const float4*)(A + (size_t)gr * 128 + c + 4);
      }
      tmp[0]=f2bf(v0.x); tmp[1]=f2bf(v0.y); tmp[2]=f2bf(v0.z); tmp[3]=f2bf(v0.w);
      tmp[4]=f2bf(v1.x); tmp[5]=f2bf(v1.y); tmp[6]=f2bf(v1.z); tmp[7]=f2bf(v1.w);
    } else {
      const unsigned short* A = (const unsigned short*)Ain;
      short8 v = {};
      if (gr < n) v = *(const short8*)(A + (size_t)gr * 128 + c);
      *(short8*)tmp = v;
    }
    int g = (c >> 3) ^ (r & 7);
    *(short8*)((char*)At + r * 256 + g * 16) = *(const short8*)tmp;
  }

  bf16x8 bfr[4];
  #pragma unroll
  for (int kk = 0; kk < 4; kk++){
    short8 tmp;
    #pragma unroll
    for (int j = 0; j < 8; j++){
      float wv = W[(kk * 32 + lg * 8 + j) * 128 + (w * 16 + ln)];
      tmp[j] = (short)f2bf(wv);
    }
    bfr[kk] = __builtin_bit_cast(bf16x8, tmp);
  }

  f32x4 acc[8];
  #pragma unroll
  for (int m = 0; m < 8; m++) acc[m] = (f32x4){0.f,0.f,0.f,0.f};

  __syncthreads();

  #pragma unroll
  for (int m = 0; m < 8; m++){
    int row = m * 16 + ln;
    #pragma unroll
    for (int kk = 0; kk < 4; kk++){
      int g = (kk * 4 + lg) ^ (row & 7);
      short8 av = *(const short8*)((const char*)At + row * 256 + g * 16);
      acc[m] = __builtin_amdgcn_mfma_f32_16x16x32_bf16(
          __builtin_bit_cast(bf16x8, av), bfr[kk], acc[m], 0, 0, 0);
    }
  }

  __syncthreads();
  unsigned char* L = (unsigned char*)At;   // reuse as [128][80] nibble-pair buffer

  // feature f = w*16+ln; even f -> low nibble of byte f/2. Partner nibble via shfl_xor(1).
  #pragma unroll
  for (int m = 0; m < 8; m++){
    #pragma unroll
    for (int r = 0; r < 4; r++){
      int row = m * 16 + lg * 4 + r;
      unsigned nib = enc_fp4(dl[row] * acc[m][r]);
      unsigned pn = (unsigned)__shfl_xor((int)nib, 1);
      if ((ln & 1) == 0)
        L[row * 80 + w * 8 + (ln >> 1)] = (unsigned char)(nib | (pn << 4));
    }
  }
  __syncthreads();

  {
    int r = t >> 2, c = (t & 3) * 16;
    int gr = rowBase + r;
    if (gr < n)
      *(uint4*)(G4 + (size_t)gr * 64 + c) = *(const uint4*)(L + r * 80 + c);
  }
}

// ---------------- SpMM: 16 lanes/row, 1 dword (8 fp4) per lane; unroll 8/4/1 ----------------
// LAST=false: H(bf16) = relu(dinv*agg + b)
// LAST=true : tvec[row] = dinv * dot(relu(dinv*agg + b), W3)   (H never materialized)
// decode scale 0.25 folded into dinv.

template<bool LAST>
__global__ __launch_bounds__(256) void k_spmm(const unsigned* __restrict__ G4, const int* __restrict__ rowptr,
    const int* __restrict__ colv, const float* __restrict__ dinv, const float* __restrict__ bias,
    const float* __restrict__ W3, unsigned* __restrict__ H, float* __restrict__ tvec, int n)
{
  int tid = blockIdx.x * 256 + threadIdx.x;
  int row = tid >> 4;
  int gl  = tid & 15;
  if (row >= n) return;

  float acc[8] = {0,0,0,0,0,0,0,0};
  add8_fp4(acc, G4[(size_t)row * 16 + gl]);     // self loop
  int e = rowptr[row], e1 = rowptr[row + 1];

  for (; e + 8 <= e1; e += 8){
    int s0 = colv[e    ], s1 = colv[e + 1], s2 = colv[e + 2], s3 = colv[e + 3];
    int s4 = colv[e + 4], s5 = colv[e + 5], s6 = colv[e + 6], s7 = colv[e + 7];
    unsigned v0 = G4[(size_t)s0 * 16 + gl];
    unsigned v1 = G4[(size_t)s1 * 16 + gl];
    unsigned v2 = G4[(size_t)s2 * 16 + gl];
    unsigned v3 = G4[(size_t)s3 * 16 + gl];
    unsigned v4 = G4[(size_t)s4 * 16 + gl];
    unsigned v5 = G4[(size_t)s5 * 16 + gl];
    unsigned v6 = G4[(size_t)s6 * 16 + gl];
    unsigned v7 = G4[(size_t)s7 * 16 + gl];
    add8_fp4(acc, v0); add8_fp4(acc, v1); add8_fp4(acc, v2); add8_fp4(acc, v3);
    add8_fp4(acc, v4); add8_fp4(acc, v5); add8_fp4(acc, v6); add8_fp4(acc, v7);
  }
  for (; e + 4 <= e1; e += 4){
    int s0 = colv[e], s1 = colv[e + 1], s2 = colv[e + 2], s3 = colv[e + 3];
    unsigned v0 = G4[(size_t)s0 * 16 + gl];
    unsigned v1 = G4[(size_t)s1 * 16 + gl];
    unsigned v2 = G4[(size_t)s2 * 16 + gl];
    unsigned v3 = G4[(size_t)s3 * 16 + gl];
    add8_fp4(acc, v0); add8_fp4(acc, v1); add8_fp4(acc, v2); add8_fp4(acc, v3);
  }
  for (; e < e1; ++e) add8_fp4(acc, G4[(size_t)colv[e] * 16 + gl]);

  float dv  = dinv[row];
  float dvq = dv * 0.25f;                       // fp4 encode scale compensation
  float r[8];
  {
    float4 b0 = *(const float4*)(bias + gl * 8);
    float4 b1 = *(const float4*)(bias + gl * 8 + 4);
    r[0] = fmaxf(fmaf(dvq, acc[0], b0.x), 0.f);
    r[1] = fmaxf(fmaf(dvq, acc[1], b0.y), 0.f);
    r[2] = fmaxf(fmaf(dvq, acc[2], b0.z), 0.f);
    r[3] = fmaxf(fmaf(dvq, acc[3], b0.w), 0.f);
    r[4] = fmaxf(fmaf(dvq, acc[4], b1.x), 0.f);
    r[5] = fmaxf(fmaf(dvq, acc[5], b1.y), 0.f);
    r[6] = fmaxf(fmaf(dvq, acc[6], b1.z), 0.f);
    r[7] = fmaxf(fmaf(dvq, acc[7], b1.w), 0.f);
  }

  if constexpr (!LAST){
    uint4 o;
    o.x = (unsigned)f2bf(r[0]) | ((unsigned)f2bf(r[1]) << 16);
    o.y = (unsigned)f2bf(r[2]) | ((unsigned)f2bf(r[3]) << 16);
    o.z = (unsigned)f2bf(r[4]) | ((unsigned)f2bf(r[5]) << 16);
    o.w = (unsigned)f2bf(r[6]) | ((unsigned)f2bf(r[7]) << 16);
    *(uint4*)(H + (size_t)row * 64 + gl * 4) = o;
  } else {
    float4 w0 = *(const float4*)(W3 + gl * 8);
    float4 w1 = *(const float4*)(W3 + gl * 8 + 4);
    float s = r[0]*w0.x + r[1]*w0.y + r[2]*w0.z + r[3]*w0.w
            + r[4]*w1.x + r[5]*w1.y + r[6]*w1.z + r[7]*w1.w;
    s += __shfl_xor(s, 1); s += __shfl_xor(s, 2);
    s += __shfl_xor(s, 4); s += __shfl_xor(s, 8);
    if (gl == 0) tvec[row] = dv * s;
  }
}

// ---------------- layer 3 final ----------------

__global__ __launch_bounds__(256) void k_final3(const float* __restrict__ tvec, const int* __restrict__ rowptr,
    const int* __restrict__ colv, const float* __restrict__ dinv, const float* __restrict__ b3,
    const float* __restrict__ x, float* __restrict__ out, int n)
{
  int tid = blockIdx.x * 256 + threadIdx.x;
  int row = tid >> 4;
  int gl  = tid & 15;
  if (row >= n) return;
  float s = 0.f;
  int e0 = rowptr[row], e1 = rowptr[row + 1];
  for (int e = e0 + gl; e < e1; e += 16) s += tvec[colv[e]];
  s += __shfl_xor(s, 1); s += __shfl_xor(s, 2);
  s += __shfl_xor(s, 4); s += __shfl_xor(s, 8);
  if (gl == 0){
    s += tvec[row];
    float v = fmaxf(fmaf(dinv[row], s, b3[0]), 0.f);
    out[row] = v + x[(size_t)row * 128 + 127];
  }
}

// ---------------- launch ----------------

extern "C" void kernel_launch(void* const* d_in, const int* in_sizes, int n_in,
                              void* d_out, int out_size, void* d_ws, size_t ws_size,
                              hipStream_t stream)
{
  const float* x  = (const float*)d_in[0];
  const int*   ei = (const int*)d_in[1];
  const float* W1 = (const float*)d_in[3];
  const float* b1 = (const float*)d_in[4];
  const float* W2 = (const float*)d_in[5];
  const float* b2 = (const float*)d_in[6];
  const float* W3 = (const float*)d_in[7];
  const float* b3 = (const float*)d_in[8];
  float* out = (float*)d_out;

  const int N = in_sizes[0] / 128;
  const int E = in_sizes[1] / 2;
  const int* src = ei;
  const int* dst = ei + E;
  const int NB = (N + 127) >> 7;

  char* wsb = (char*)d_ws;
  size_t off = 0;
  auto carve = [&](size_t bytes) -> void* {
    void* p = wsb + off;
    off += bytes;
    off = (off + 255) & ~(size_t)255;
    return p;
  };
  float*    dinv   = (float*)carve((size_t)N * 4);
  int*      rowptr = (int*)carve((size_t)(N + 1) * 4);
  int*      colv   = (int*)carve((size_t)E * 4);
  int*      bstart = (int*)carve((size_t)(NB + 1) * 4);
  int*      bpos   = (int*)carve((size_t)NB * 4);
  float*    tvec   = (float*)carve((size_t)N * 4);
  unsigned char* G4 = (unsigned char*)carve((size_t)N * 64);   // fp4 N x 128 (64B/row)
  unsigned* H      = (unsigned*)carve((size_t)N * 256);        // bf16 N x 128 (layer1 only)
  unsigned* ebuf   = (unsigned*)H;                             // overlay: NB*BCAP*4 <= N*256

  hipMemsetAsync(bpos, 0, (size_t)NB * 4, stream);
  k_part  <<<(E + PART_C - 1) / PART_C, 1024, 0, stream>>>(src, dst, bpos, ebuf, E, NB);
  k_cscan <<<1, 1024, 0, stream>>>(bpos, bstart, rowptr, NB, N, E);
  k_bsort <<<NB, 256, 0, stream>>>(ebuf, bpos, bstart, rowptr, colv, dinv, N);

  // layer 1
  k_gemm_mfma<true ><<<(N + 127) / 128, 512, 0, stream>>>(x, W1, dinv, G4, N);
  k_spmm<false><<<((size_t)N * 16 + 255) / 256, 256, 0, stream>>>((const unsigned*)G4, rowptr, colv, dinv, b1, nullptr, H, nullptr, N);
  // layer 2
  k_gemm_mfma<false><<<(N + 127) / 128, 512, 0, stream>>>(H, W2, dinv, G4, N);
  // layer 2 aggregation fused with layer-3 GEMV epilogue
  k_spmm<true ><<<((size_t)N * 16 + 255) / 256, 256, 0, stream>>>((const unsigned*)G4, rowptr, colv, dinv, b2, W3, nullptr, tvec, N);
  // layer 3 aggregation + residual
  k_final3<<<((size_t)N * 16 + 255) / 256, 256, 0, stream>>>(tvec, rowptr, colv, dinv, b3, x, out, N);
}

// Round 14
// 150.069 us; speedup vs baseline: 1.1603x; 1.1603x over previous
//
#include <hip/hip_runtime.h>
#include <hip/hip_bf16.h>

typedef __attribute__((ext_vector_type(8))) short short8;
typedef __attribute__((ext_vector_type(8))) __bf16 bf16x8;
typedef __attribute__((ext_vector_type(4))) float f32x4;

static __device__ __forceinline__ float bflo(unsigned u){ return __uint_as_float(u << 16); }
static __device__ __forceinline__ float bfhi(unsigned u){ return __uint_as_float(u & 0xffff0000u); }
static __device__ __forceinline__ unsigned short f2bf(float f){
  unsigned u = __float_as_uint(f);
  unsigned r = u + 0x7fffu + ((u >> 16) & 1u);
  return (unsigned short)(r >> 16);
}

// ---- fp8 e4m3 conversions ----
#if __has_builtin(__builtin_amdgcn_cvt_pk_fp8_f32)
static __device__ __forceinline__ unsigned char f2e4m3(float f){
  return (unsigned char)(__builtin_amdgcn_cvt_pk_fp8_f32(f, 0.f, 0, false) & 0xff);
}
#else
static __device__ __forceinline__ unsigned char f2e4m3(float f){
  unsigned s = (__float_as_uint(f) >> 31) << 7;
  float a = fabsf(f);
  if (a >= 448.f) return (unsigned char)(s | 0x7e);
  if (a < 0.0009765625f) return (unsigned char)s;
  if (a >= 0.015625f){
    int e; float m = frexpf(a, &e);
    int q = (int)rintf(m * 16.f);
    int E = e - 1 + 7;
    if (q == 16){ q = 8; E++; }
    if (E >= 16) return (unsigned char)(s | 0x7e);
    return (unsigned char)(s | (E << 3) | (q - 8));
  } else {
    int q = (int)rintf(a * 512.f);
    if (q > 7) return (unsigned char)(s | 0x08);
    return (unsigned char)(s | q);
  }
}
#endif

#if __has_builtin(__builtin_amdgcn_cvt_pk_f32_fp8)
static __device__ __forceinline__ float4 e4m3x4_to_f32(unsigned u){
  auto lo = __builtin_amdgcn_cvt_pk_f32_fp8((int)u, false);
  auto hi = __builtin_amdgcn_cvt_pk_f32_fp8((int)u, true);
  return make_float4(lo[0], lo[1], hi[0], hi[1]);
}
#else
static __device__ __forceinline__ float e4m3_1(unsigned b){
  unsigned s = b >> 7, e = (b >> 3) & 15, m = b & 7;
  float v = e ? ldexpf((float)(8 + m) * 0.125f, (int)e - 7) : ldexpf((float)m * 0.125f, -6);
  return s ? -v : v;
}
static __device__ __forceinline__ float4 e4m3x4_to_f32(unsigned u){
  return make_float4(e4m3_1(u & 255), e4m3_1((u >> 8) & 255), e4m3_1((u >> 16) & 255), e4m3_1(u >> 24));
}
#endif

static __device__ __forceinline__ void add8(float* acc, uint2 u){
  float4 a = e4m3x4_to_f32(u.x), b = e4m3x4_to_f32(u.y);
  acc[0] += a.x; acc[1] += a.y; acc[2] += a.z; acc[3] += a.w;
  acc[4] += b.x; acc[5] += b.y; acc[6] += b.z; acc[7] += b.w;
}

#define NBMAX  1024
#define PART_C 4096
#define STCAP  4096
#define BCAP   6144   // per-bucket ebuf capacity (mean 2046, +90 sigma)

// ---------------- bucket pipeline (no pre-count pass, no separate scan kernel) ----------------

__global__ __launch_bounds__(1024) void k_part(const int* __restrict__ src, const int* __restrict__ dst,
    int* __restrict__ bpos, unsigned* __restrict__ ebuf, int E, int NB)
{
  __shared__ int hist[NBMAX + 1];
  __shared__ int hist2[NBMAX];
  __shared__ int gbase[NBMAX];
  __shared__ int sc[1024];
  __shared__ unsigned staged[PART_C];
  __shared__ unsigned short sbkt[PART_C];

  const int t = threadIdx.x;
  const int base = blockIdx.x * PART_C;

  for (int i = t; i < NBMAX; i += 1024){ hist[i] = 0; hist2[i] = 0; }
  __syncthreads();

  unsigned up[4];
  int bb[4];
  #pragma unroll
  for (int j = 0; j < 4; j++){
    int e = base + j * 1024 + t;
    if (e < E){
      int s = src[e], d = dst[e];
      bb[j] = d >> 7;
      up[j] = ((unsigned)s << 7) | (unsigned)(d & 127);
      atomicAdd(&hist[bb[j]], 1);
    } else bb[j] = -1;
  }
  __syncthreads();

  int v = (t < NB) ? hist[t] : 0;
  sc[t] = v; __syncthreads();
  for (int off = 1; off < 1024; off <<= 1){
    int u = (t >= off) ? sc[t - off] : 0;
    __syncthreads();
    sc[t] += u;
    __syncthreads();
  }
  int incl = sc[t];
  if (t < NB) hist[t] = incl - v;
  if (t == NB - 1) hist[NB] = incl;
  if (t < NB && v > 0) gbase[t] = t * BCAP + atomicAdd(&bpos[t], v);
  __syncthreads();

  #pragma unroll
  for (int j = 0; j < 4; j++){
    if (bb[j] >= 0){
      int r = atomicAdd(&hist2[bb[j]], 1);
      int p = hist[bb[j]] + r;
      staged[p] = up[j];
      sbkt[p] = (unsigned short)bb[j];
    }
  }
  __syncthreads();

  int total = hist[NB];
  for (int i = t; i < total; i += 1024){
    int b = sbkt[i];
    ebuf[gbase[b] + (i - hist[b])] = staged[i];
  }
}

// fine sort within each 128-row bucket; computes its own compact write base from cnts;
// emits rowptr + dinv (and rowptr[N]=E from the last block)
__global__ __launch_bounds__(256) void k_bsort(const unsigned* __restrict__ ebuf, const int* __restrict__ cnts,
    int* __restrict__ rowptr, int* __restrict__ colv, float* __restrict__ dinv, int n, int E, int NB)
{
  __shared__ int cl[128];
  __shared__ int sc2[256];
  __shared__ unsigned stg[STCAP];

  const int t = threadIdx.x;
  const int b = blockIdx.x;
  const int r0 = b << 7;
  const int rbeg = b * BCAP;
  const int total = cnts[b];

  // compact write base = sum of cnts[0..b)
  {
    int psum = 0;
    for (int i = t; i < b; i += 256) psum += cnts[i];
    sc2[t] = psum; __syncthreads();
    for (int off = 128; off; off >>= 1){
      if (t < off) sc2[t] += sc2[t + off];
      __syncthreads();
    }
  }
  const int wbeg = sc2[0];
  __syncthreads();

  if (b == NB - 1 && t == 0) rowptr[n] = E;

  if (t < 128) cl[t] = 0;
  __syncthreads();
  for (int i = t; i < total; i += 256) atomicAdd(&cl[ebuf[rbeg + i] & 127u], 1);
  __syncthreads();

  int v = (t < 128) ? cl[t] : 0;
  sc2[t] = v; __syncthreads();
  for (int off = 1; off < 256; off <<= 1){
    int u = (t >= off) ? sc2[t - off] : 0;
    __syncthreads();
    sc2[t] += u;
    __syncthreads();
  }
  int excl = sc2[t] - v;
  if (t < 128){
    int node = r0 + t;
    if (node < n){
      rowptr[node] = wbeg + excl;
      dinv[node]   = rsqrtf((float)(v + 1));
    }
    cl[t] = excl;
  }
  __syncthreads();

  if (total <= STCAP){
    for (int i = t; i < total; i += 256){
      unsigned u = ebuf[rbeg + i];
      int p = atomicAdd(&cl[u & 127u], 1);
      stg[p] = u >> 7;
    }
    __syncthreads();
    for (int i = t; i < total; i += 256) colv[wbeg + i] = (int)stg[i];
  } else {
    for (int i = t; i < total; i += 256){
      unsigned u = ebuf[rbeg + i];
      int p = atomicAdd(&cl[u & 127u], 1);
      colv[wbeg + p] = (int)(u >> 7);
    }
  }
}

// ---------------- MFMA GEMM: G8[i,:] = fp8( dinv[i] * (A[i,:] @ W) ) ----------------

template<bool AF32>
__global__ __launch_bounds__(512) void k_gemm_mfma(const void* __restrict__ Ain, const float* __restrict__ W,
    const float* __restrict__ dinv, unsigned char* __restrict__ G8, int n)
{
  __shared__ unsigned short At[128 * 136];
  __shared__ float dl[128];

  const int t = threadIdx.x;
  const int rowBase = blockIdx.x * 128;
  const int w  = t >> 6;
  const int l  = t & 63;
  const int ln = l & 15;
  const int lg = l >> 4;

  if (t < 128){
    int gr = rowBase + t;
    dl[t] = (gr < n) ? dinv[gr] : 0.f;
  }

  #pragma unroll
  for (int i = 0; i < 4; i++){
    int flat = i * 4096 + t * 8;
    int r = flat >> 7, c = flat & 127;
    int gr = rowBase + r;
    unsigned short tmp[8];
    if constexpr (AF32){
      const float* A = (const float*)Ain;
      float4 v0 = make_float4(0.f,0.f,0.f,0.f), v1 = v0;
      if (gr < n){
        v0 = *(const float4*)(A + (size_t)gr * 128 + c);
        v1 = *(const float4*)(A + (size_t)gr * 128 + c + 4);
      }
      tmp[0]=f2bf(v0.x); tmp[1]=f2bf(v0.y); tmp[2]=f2bf(v0.z); tmp[3]=f2bf(v0.w);
      tmp[4]=f2bf(v1.x); tmp[5]=f2bf(v1.y); tmp[6]=f2bf(v1.z); tmp[7]=f2bf(v1.w);
    } else {
      const unsigned short* A = (const unsigned short*)Ain;
      short8 v = {};
      if (gr < n) v = *(const short8*)(A + (size_t)gr * 128 + c);
      *(short8*)tmp = v;
    }
    int g = (c >> 3) ^ (r & 7);
    *(short8*)((char*)At + r * 256 + g * 16) = *(const short8*)tmp;
  }

  bf16x8 bfr[4];
  #pragma unroll
  for (int kk = 0; kk < 4; kk++){
    short8 tmp;
    #pragma unroll
    for (int j = 0; j < 8; j++){
      float wv = W[(kk * 32 + lg * 8 + j) * 128 + (w * 16 + ln)];
      tmp[j] = (short)f2bf(wv);
    }
    bfr[kk] = __builtin_bit_cast(bf16x8, tmp);
  }

  f32x4 acc[8];
  #pragma unroll
  for (int m = 0; m < 8; m++) acc[m] = (f32x4){0.f,0.f,0.f,0.f};

  __syncthreads();

  #pragma unroll
  for (int m = 0; m < 8; m++){
    int row = m * 16 + ln;
    #pragma unroll
    for (int kk = 0; kk < 4; kk++){
      int g = (kk * 4 + lg) ^ (row & 7);
      short8 av = *(const short8*)((const char*)At + row * 256 + g * 16);
      acc[m] = __builtin_amdgcn_mfma_f32_16x16x32_bf16(
          __builtin_bit_cast(bf16x8, av), bfr[kk], acc[m], 0, 0, 0);
    }
  }

  __syncthreads();
  unsigned char* At8 = (unsigned char*)At;

  #pragma unroll
  for (int m = 0; m < 8; m++){
    #pragma unroll
    for (int r = 0; r < 4; r++){
      int row = m * 16 + lg * 4 + r;
      At8[row * 136 + w * 16 + ln] = f2e4m3(dl[row] * acc[m][r]);
    }
  }
  __syncthreads();

  {
    int r = t >> 2, c = (t & 3) * 32;
    int gr = rowBase + r;
    if (gr < n){
      uint4 a = *(const uint4*)(At8 + r * 136 + c);
      uint4 b = *(const uint4*)(At8 + r * 136 + c + 16);
      *(uint4*)(G8 + (size_t)gr * 128 + c)      = a;
      *(uint4*)(G8 + (size_t)gr * 128 + c + 16) = b;
    }
  }
}

// ---------------- SpMM: 16 lanes/row, uint2 (8 fp8) per lane; unroll 8/4/1 ----------------
// LAST=false: H(bf16) = relu(dinv*agg + b)
// LAST=true : tvec[row] = dinv * dot(relu(dinv*agg + b), W3)   (H never materialized)

template<bool LAST>
__global__ __launch_bounds__(256) void k_spmm(const uint2* __restrict__ G8, const int* __restrict__ rowptr,
    const int* __restrict__ colv, const float* __restrict__ dinv, const float* __restrict__ bias,
    const float* __restrict__ W3, unsigned* __restrict__ H, float* __restrict__ tvec, int n)
{
  int tid = blockIdx.x * 256 + threadIdx.x;
  int row = tid >> 4;
  int gl  = tid & 15;
  if (row >= n) return;

  float acc[8] = {0,0,0,0,0,0,0,0};
  add8(acc, G8[(size_t)row * 16 + gl]);         // self loop
  int e = rowptr[row], e1 = rowptr[row + 1];

  for (; e + 8 <= e1; e += 8){
    int s0 = colv[e    ], s1 = colv[e + 1], s2 = colv[e + 2], s3 = colv[e + 3];
    int s4 = colv[e + 4], s5 = colv[e + 5], s6 = colv[e + 6], s7 = colv[e + 7];
    uint2 v0 = G8[(size_t)s0 * 16 + gl];
    uint2 v1 = G8[(size_t)s1 * 16 + gl];
    uint2 v2 = G8[(size_t)s2 * 16 + gl];
    uint2 v3 = G8[(size_t)s3 * 16 + gl];
    uint2 v4 = G8[(size_t)s4 * 16 + gl];
    uint2 v5 = G8[(size_t)s5 * 16 + gl];
    uint2 v6 = G8[(size_t)s6 * 16 + gl];
    uint2 v7 = G8[(size_t)s7 * 16 + gl];
    add8(acc, v0); add8(acc, v1); add8(acc, v2); add8(acc, v3);
    add8(acc, v4); add8(acc, v5); add8(acc, v6); add8(acc, v7);
  }
  for (; e + 4 <= e1; e += 4){
    int s0 = colv[e], s1 = colv[e + 1], s2 = colv[e + 2], s3 = colv[e + 3];
    uint2 v0 = G8[(size_t)s0 * 16 + gl];
    uint2 v1 = G8[(size_t)s1 * 16 + gl];
    uint2 v2 = G8[(size_t)s2 * 16 + gl];
    uint2 v3 = G8[(size_t)s3 * 16 + gl];
    add8(acc, v0); add8(acc, v1); add8(acc, v2); add8(acc, v3);
  }
  for (; e < e1; ++e) add8(acc, G8[(size_t)colv[e] * 16 + gl]);

  float dv = dinv[row];
  float r[8];
  {
    float4 b0 = *(const float4*)(bias + gl * 8);
    float4 b1 = *(const float4*)(bias + gl * 8 + 4);
    r[0] = fmaxf(fmaf(dv, acc[0], b0.x), 0.f);
    r[1] = fmaxf(fmaf(dv, acc[1], b0.y), 0.f);
    r[2] = fmaxf(fmaf(dv, acc[2], b0.z), 0.f);
    r[3] = fmaxf(fmaf(dv, acc[3], b0.w), 0.f);
    r[4] = fmaxf(fmaf(dv, acc[4], b1.x), 0.f);
    r[5] = fmaxf(fmaf(dv, acc[5], b1.y), 0.f);
    r[6] = fmaxf(fmaf(dv, acc[6], b1.z), 0.f);
    r[7] = fmaxf(fmaf(dv, acc[7], b1.w), 0.f);
  }

  if constexpr (!LAST){
    uint4 o;
    o.x = (unsigned)f2bf(r[0]) | ((unsigned)f2bf(r[1]) << 16);
    o.y = (unsigned)f2bf(r[2]) | ((unsigned)f2bf(r[3]) << 16);
    o.z = (unsigned)f2bf(r[4]) | ((unsigned)f2bf(r[5]) << 16);
    o.w = (unsigned)f2bf(r[6]) | ((unsigned)f2bf(r[7]) << 16);
    *(uint4*)(H + (size_t)row * 64 + gl * 4) = o;
  } else {
    float4 w0 = *(const float4*)(W3 + gl * 8);
    float4 w1 = *(const float4*)(W3 + gl * 8 + 4);
    float s = r[0]*w0.x + r[1]*w0.y + r[2]*w0.z + r[3]*w0.w
            + r[4]*w1.x + r[5]*w1.y + r[6]*w1.z + r[7]*w1.w;
    s += __shfl_xor(s, 1); s += __shfl_xor(s, 2);
    s += __shfl_xor(s, 4); s += __shfl_xor(s, 8);
    if (gl == 0) tvec[row] = dv * s;
  }
}

// ---------------- layer 3 final ----------------

__global__ __launch_bounds__(256) void k_final3(const float* __restrict__ tvec, const int* __restrict__ rowptr,
    const int* __restrict__ colv, const float* __restrict__ dinv, const float* __restrict__ b3,
    const float* __restrict__ x, float* __restrict__ out, int n)
{
  int tid = blockIdx.x * 256 + threadIdx.x;
  int row = tid >> 4;
  int gl  = tid & 15;
  if (row >= n) return;
  float s = 0.f;
  int e0 = rowptr[row], e1 = rowptr[row + 1];
  for (int e = e0 + gl; e < e1; e += 16) s += tvec[colv[e]];
  s += __shfl_xor(s, 1); s += __shfl_xor(s, 2);
  s += __shfl_xor(s, 4); s += __shfl_xor(s, 8);
  if (gl == 0){
    s += tvec[row];
    float v = fmaxf(fmaf(dinv[row], s, b3[0]), 0.f);
    out[row] = v + x[(size_t)row * 128 + 127];
  }
}

// ---------------- launch ----------------

extern "C" void kernel_launch(void* const* d_in, const int* in_sizes, int n_in,
                              void* d_out, int out_size, void* d_ws, size_t ws_size,
                              hipStream_t stream)
{
  const float* x  = (const float*)d_in[0];
  const int*   ei = (const int*)d_in[1];
  const float* W1 = (const float*)d_in[3];
  const float* b1 = (const float*)d_in[4];
  const float* W2 = (const float*)d_in[5];
  const float* b2 = (const float*)d_in[6];
  const float* W3 = (const float*)d_in[7];
  const float* b3 = (const float*)d_in[8];
  float* out = (float*)d_out;

  const int N = in_sizes[0] / 128;
  const int E = in_sizes[1] / 2;
  const int* src = ei;
  const int* dst = ei + E;
  const int NB = (N + 127) >> 7;

  char* wsb = (char*)d_ws;
  size_t off = 0;
  auto carve = [&](size_t bytes) -> void* {
    void* p = wsb + off;
    off += bytes;
    off = (off + 255) & ~(size_t)255;
    return p;
  };
  float*    dinv   = (float*)carve((size_t)N * 4);
  int*      rowptr = (int*)carve((size_t)(N + 1) * 4);
  int*      colv   = (int*)carve((size_t)E * 4);
  int*      bpos   = (int*)carve((size_t)NB * 4);
  float*    tvec   = (float*)carve((size_t)N * 4);
  unsigned char* G8 = (unsigned char*)carve((size_t)N * 128);  // fp8 N x 128
  unsigned* H      = (unsigned*)carve((size_t)N * 256);        // bf16 N x 128 (layer1 only)
  unsigned* ebuf   = (unsigned*)H;                             // overlay: NB*BCAP*4 <= N*256

  hipMemsetAsync(bpos, 0, (size_t)NB * 4, stream);
  k_part  <<<(E + PART_C - 1) / PART_C, 1024, 0, stream>>>(src, dst, bpos, ebuf, E, NB);
  k_bsort <<<NB, 256, 0, stream>>>(ebuf, bpos, rowptr, colv, dinv, N, E, NB);

  // layer 1
  k_gemm_mfma<true ><<<(N + 127) / 128, 512, 0, stream>>>(x, W1, dinv, G8, N);
  k_spmm<false><<<((size_t)N * 16 + 255) / 256, 256, 0, stream>>>((const uint2*)G8, rowptr, colv, dinv, b1, nullptr, H, nullptr, N);
  // layer 2
  k_gemm_mfma<false><<<(N + 127) / 128, 512, 0, stream>>>(H, W2, dinv, G8, N);
  // layer 2 aggregation fused with layer-3 GEMV epilogue
  k_spmm<true ><<<((size_t)N * 16 + 255) / 256, 256, 0, stream>>>((const uint2*)G8, rowptr, colv, dinv, b2, W3, nullptr, tvec, N);
  // layer 3 aggregation + residual
  k_final3<<<((size_t)N * 16 + 255) / 256, 256, 0, stream>>>(tvec, rowptr, colv, dinv, b3, x, out, N);
}

// Round 15
// 149.309 us; speedup vs baseline: 1.1662x; 1.0051x over previous
//
#include <hip/hip_runtime.h>
#include <hip/hip_bf16.h>

typedef __attribute__((ext_vector_type(8))) short short8;
typedef __attribute__((ext_vector_type(8))) __bf16 bf16x8;
typedef __attribute__((ext_vector_type(4))) float f32x4;

static __device__ __forceinline__ unsigned short f2bf(float f){
  unsigned u = __float_as_uint(f);
  unsigned r = u + 0x7fffu + ((u >> 16) & 1u);
  return (unsigned short)(r >> 16);
}

// ---- fp8 e4m3 conversions ----
#if __has_builtin(__builtin_amdgcn_cvt_pk_fp8_f32)
static __device__ __forceinline__ unsigned char f2e4m3(float f){
  return (unsigned char)(__builtin_amdgcn_cvt_pk_fp8_f32(f, 0.f, 0, false) & 0xff);
}
static __device__ __forceinline__ unsigned pk4_fp8(float a, float b, float c, float d){
  int v = __builtin_amdgcn_cvt_pk_fp8_f32(a, b, 0, false);
  v = __builtin_amdgcn_cvt_pk_fp8_f32(c, d, v, true);
  return (unsigned)v;
}
#else
static __device__ __forceinline__ unsigned char f2e4m3(float f){
  unsigned s = (__float_as_uint(f) >> 31) << 7;
  float a = fabsf(f);
  if (a >= 448.f) return (unsigned char)(s | 0x7e);
  if (a < 0.0009765625f) return (unsigned char)s;
  if (a >= 0.015625f){
    int e; float m = frexpf(a, &e);
    int q = (int)rintf(m * 16.f);
    int E = e - 1 + 7;
    if (q == 16){ q = 8; E++; }
    if (E >= 16) return (unsigned char)(s | 0x7e);
    return (unsigned char)(s | (E << 3) | (q - 8));
  } else {
    int q = (int)rintf(a * 512.f);
    if (q > 7) return (unsigned char)(s | 0x08);
    return (unsigned char)(s | q);
  }
}
static __device__ __forceinline__ unsigned pk4_fp8(float a, float b, float c, float d){
  return (unsigned)f2e4m3(a) | ((unsigned)f2e4m3(b) << 8)
       | ((unsigned)f2e4m3(c) << 16) | ((unsigned)f2e4m3(d) << 24);
}
#endif

#if __has_builtin(__builtin_amdgcn_cvt_pk_f32_fp8)
static __device__ __forceinline__ float4 e4m3x4_to_f32(unsigned u){
  auto lo = __builtin_amdgcn_cvt_pk_f32_fp8((int)u, false);
  auto hi = __builtin_amdgcn_cvt_pk_f32_fp8((int)u, true);
  return make_float4(lo[0], lo[1], hi[0], hi[1]);
}
#else
static __device__ __forceinline__ float e4m3_1(unsigned b){
  unsigned s = b >> 7, e = (b >> 3) & 15, m = b & 7;
  float v = e ? ldexpf((float)(8 + m) * 0.125f, (int)e - 7) : ldexpf((float)m * 0.125f, -6);
  return s ? -v : v;
}
static __device__ __forceinline__ float4 e4m3x4_to_f32(unsigned u){
  return make_float4(e4m3_1(u & 255), e4m3_1((u >> 8) & 255), e4m3_1((u >> 16) & 255), e4m3_1(u >> 24));
}
#endif

static __device__ __forceinline__ void add8(float* acc, uint2 u){
  float4 a = e4m3x4_to_f32(u.x), b = e4m3x4_to_f32(u.y);
  acc[0] += a.x; acc[1] += a.y; acc[2] += a.z; acc[3] += a.w;
  acc[4] += b.x; acc[5] += b.y; acc[6] += b.z; acc[7] += b.w;
}

#define NBMAX  1024
#define PART_C 4096
#define STCAP  4096
#define BCAP   6144   // per-bucket ebuf capacity (mean 2046, +90 sigma)

// ---------------- bucket pipeline ----------------

__global__ __launch_bounds__(1024) void k_part(const int* __restrict__ src, const int* __restrict__ dst,
    int* __restrict__ bpos, unsigned* __restrict__ ebuf, int E, int NB)
{
  __shared__ int hist[NBMAX + 1];
  __shared__ int hist2[NBMAX];
  __shared__ int gbase[NBMAX];
  __shared__ int wsum[16];
  __shared__ unsigned staged[PART_C];
  __shared__ unsigned short sbkt[PART_C];

  const int t = threadIdx.x;
  const int lane = t & 63;
  const int wv = t >> 6;
  const int base = blockIdx.x * PART_C;

  for (int i = t; i < NBMAX; i += 1024){ hist[i] = 0; hist2[i] = 0; }
  __syncthreads();

  unsigned up[4];
  int bb[4];
  #pragma unroll
  for (int j = 0; j < 4; j++){
    int e = base + j * 1024 + t;
    if (e < E){
      int s = src[e], d = dst[e];
      bb[j] = d >> 7;
      up[j] = ((unsigned)s << 7) | (unsigned)(d & 127);
      atomicAdd(&hist[bb[j]], 1);
    } else bb[j] = -1;
  }
  __syncthreads();

  // wave-shuffle exclusive scan of hist[0..NB)
  int v = (t < NB) ? hist[t] : 0;
  int incl = v;
  #pragma unroll
  for (int off = 1; off < 64; off <<= 1){
    int u = __shfl_up(incl, off);
    if (lane >= off) incl += u;
  }
  if (lane == 63) wsum[wv] = incl;
  __syncthreads();
  if (wv == 0){
    int s = (lane < 16) ? wsum[lane] : 0;
    int is = s;
    #pragma unroll
    for (int off = 1; off < 16; off <<= 1){
      int u = __shfl_up(is, off);
      if (lane >= off) is += u;
    }
    if (lane < 16) wsum[lane] = is - s;   // exclusive wave base
  }
  __syncthreads();
  incl += wsum[wv];
  if (t < NB) hist[t] = incl - v;         // exclusive prefix
  if (t == NB - 1) hist[NB] = incl;       // block total
  if (t < NB && v > 0) gbase[t] = t * BCAP + atomicAdd(&bpos[t], v);
  __syncthreads();

  #pragma unroll
  for (int j = 0; j < 4; j++){
    if (bb[j] >= 0){
      int r = atomicAdd(&hist2[bb[j]], 1);
      int p = hist[bb[j]] + r;
      staged[p] = up[j];
      sbkt[p] = (unsigned short)bb[j];
    }
  }
  __syncthreads();

  int total = hist[NB];
  for (int i = t; i < total; i += 1024){
    int b = sbkt[i];
    ebuf[gbase[b] + (i - hist[b])] = staged[i];
  }
}

// fine sort within each 128-row bucket; computes its own compact write base from cnts;
// emits rowptr + dinv (and rowptr[N]=E from the last block)
__global__ __launch_bounds__(256) void k_bsort(const unsigned* __restrict__ ebuf, const int* __restrict__ cnts,
    int* __restrict__ rowptr, int* __restrict__ colv, float* __restrict__ dinv, int n, int E, int NB)
{
  __shared__ int cl[128];
  __shared__ int wred[4];
  __shared__ unsigned stg[STCAP];

  const int t = threadIdx.x;
  const int lane = t & 63;
  const int wv = t >> 6;
  const int b = blockIdx.x;
  const int r0 = b << 7;
  const int rbeg = b * BCAP;
  const int total = cnts[b];

  // compact write base = sum of cnts[0..b)  (wave shfl reduce, 1 barrier)
  int psum = 0;
  for (int i = t; i < b; i += 256) psum += cnts[i];
  #pragma unroll
  for (int off = 32; off; off >>= 1) psum += __shfl_xor(psum, off);
  if (lane == 0) wred[wv] = psum;
  __syncthreads();
  const int wbeg = wred[0] + wred[1] + wred[2] + wred[3];

  if (b == NB - 1 && t == 0) rowptr[n] = E;

  if (t < 128) cl[t] = 0;
  __syncthreads();
  for (int i = t; i < total; i += 256) atomicAdd(&cl[ebuf[rbeg + i] & 127u], 1);
  __syncthreads();

  // wave-shuffle exclusive scan of cl[0..128) (waves 0,1)
  int v = (t < 128) ? cl[t] : 0;
  int incl = v;
  #pragma unroll
  for (int off = 1; off < 64; off <<= 1){
    int u = __shfl_up(incl, off);
    if (lane >= off) incl += u;
  }
  if (lane == 63) wred[wv] = incl;
  __syncthreads();
  incl += (wv == 1) ? wred[0] : 0;
  int excl = incl - v;
  if (t < 128){
    int node = r0 + t;
    if (node < n){
      rowptr[node] = wbeg + excl;
      dinv[node]   = rsqrtf((float)(v + 1));
    }
    cl[t] = excl;
  }
  __syncthreads();

  if (total <= STCAP){
    for (int i = t; i < total; i += 256){
      unsigned u = ebuf[rbeg + i];
      int p = atomicAdd(&cl[u & 127u], 1);
      stg[p] = u >> 7;
    }
    __syncthreads();
    for (int i = t; i < total; i += 256) colv[wbeg + i] = (int)stg[i];
  } else {
    for (int i = t; i < total; i += 256){
      unsigned u = ebuf[rbeg + i];
      int p = atomicAdd(&cl[u & 127u], 1);
      colv[wbeg + p] = (int)(u >> 7);
    }
  }
}

// ---------------- MFMA GEMM: G8[i,:] = fp8( dinv[i] * (A[i,:] @ W) ) ----------------
// AF32=true: A is f32 row-major (layer 1).  AF32=false: A is fp8 row-major (H from spmm1).

template<bool AF32>
__global__ __launch_bounds__(512) void k_gemm_mfma(const void* __restrict__ Ain, const float* __restrict__ W,
    const float* __restrict__ dinv, unsigned char* __restrict__ G8, int n)
{
  __shared__ unsigned short At[128 * 136];
  __shared__ float dl[128];

  const int t = threadIdx.x;
  const int rowBase = blockIdx.x * 128;
  const int w  = t >> 6;
  const int l  = t & 63;
  const int ln = l & 15;
  const int lg = l >> 4;

  if (t < 128){
    int gr = rowBase + t;
    dl[t] = (gr < n) ? dinv[gr] : 0.f;
  }

  #pragma unroll
  for (int i = 0; i < 4; i++){
    int flat = i * 4096 + t * 8;
    int r = flat >> 7, c = flat & 127;
    int gr = rowBase + r;
    unsigned short tmp[8];
    if constexpr (AF32){
      const float* A = (const float*)Ain;
      float4 v0 = make_float4(0.f,0.f,0.f,0.f), v1 = v0;
      if (gr < n){
        v0 = *(const float4*)(A + (size_t)gr * 128 + c);
        v1 = *(const float4*)(A + (size_t)gr * 128 + c + 4);
      }
      tmp[0]=f2bf(v0.x); tmp[1]=f2bf(v0.y); tmp[2]=f2bf(v0.z); tmp[3]=f2bf(v0.w);
      tmp[4]=f2bf(v1.x); tmp[5]=f2bf(v1.y); tmp[6]=f2bf(v1.z); tmp[7]=f2bf(v1.w);
    } else {
      const unsigned char* A = (const unsigned char*)Ain;   // fp8 rows, 128B
      if (gr < n){
        uint2 v8 = *(const uint2*)(A + (size_t)gr * 128 + c);
        float4 lo = e4m3x4_to_f32(v8.x), hi = e4m3x4_to_f32(v8.y);
        tmp[0]=f2bf(lo.x); tmp[1]=f2bf(lo.y); tmp[2]=f2bf(lo.z); tmp[3]=f2bf(lo.w);
        tmp[4]=f2bf(hi.x); tmp[5]=f2bf(hi.y); tmp[6]=f2bf(hi.z); tmp[7]=f2bf(hi.w);
      } else {
        #pragma unroll
        for (int j = 0; j < 8; j++) tmp[j] = 0;
      }
    }
    int g = (c >> 3) ^ (r & 7);
    *(short8*)((char*)At + r * 256 + g * 16) = *(const short8*)tmp;
  }

  bf16x8 bfr[4];
  #pragma unroll
  for (int kk = 0; kk < 4; kk++){
    short8 tmp;
    #pragma unroll
    for (int j = 0; j < 8; j++){
      float wv = W[(kk * 32 + lg * 8 + j) * 128 + (w * 16 + ln)];
      tmp[j] = (short)f2bf(wv);
    }
    bfr[kk] = __builtin_bit_cast(bf16x8, tmp);
  }

  f32x4 acc[8];
  #pragma unroll
  for (int m = 0; m < 8; m++) acc[m] = (f32x4){0.f,0.f,0.f,0.f};

  __syncthreads();

  #pragma unroll
  for (int m = 0; m < 8; m++){
    int row = m * 16 + ln;
    #pragma unroll
    for (int kk = 0; kk < 4; kk++){
      int g = (kk * 4 + lg) ^ (row & 7);
      short8 av = *(const short8*)((const char*)At + row * 256 + g * 16);
      acc[m] = __builtin_amdgcn_mfma_f32_16x16x32_bf16(
          __builtin_bit_cast(bf16x8, av), bfr[kk], acc[m], 0, 0, 0);
    }
  }

  __syncthreads();
  unsigned char* At8 = (unsigned char*)At;

  #pragma unroll
  for (int m = 0; m < 8; m++){
    #pragma unroll
    for (int r = 0; r < 4; r++){
      int row = m * 16 + lg * 4 + r;
      At8[row * 136 + w * 16 + ln] = f2e4m3(dl[row] * acc[m][r]);
    }
  }
  __syncthreads();

  {
    int r = t >> 2, c = (t & 3) * 32;
    int gr = rowBase + r;
    if (gr < n){
      uint4 a = *(const uint4*)(At8 + r * 136 + c);
      uint4 b = *(const uint4*)(At8 + r * 136 + c + 16);
      *(uint4*)(G8 + (size_t)gr * 128 + c)      = a;
      *(uint4*)(G8 + (size_t)gr * 128 + c + 16) = b;
    }
  }
}

// ---------------- SpMM: 16 lanes/row, uint2 (8 fp8) per lane; unroll 8/4/1 ----------------
// LAST=false: H(fp8) = relu(dinv*agg + b)
// LAST=true : tvec[row] = dinv * dot(relu(dinv*agg + b), W3)   (H never materialized)

template<bool LAST>
__global__ __launch_bounds__(256) void k_spmm(const uint2* __restrict__ G8, const int* __restrict__ rowptr,
    const int* __restrict__ colv, const float* __restrict__ dinv, const float* __restrict__ bias,
    const float* __restrict__ W3, uint2* __restrict__ H, float* __restrict__ tvec, int n)
{
  int tid = blockIdx.x * 256 + threadIdx.x;
  int row = tid >> 4;
  int gl  = tid & 15;
  if (row >= n) return;

  float acc[8] = {0,0,0,0,0,0,0,0};
  add8(acc, G8[(size_t)row * 16 + gl]);         // self loop
  int e = rowptr[row], e1 = rowptr[row + 1];

  for (; e + 8 <= e1; e += 8){
    int s0 = colv[e    ], s1 = colv[e + 1], s2 = colv[e + 2], s3 = colv[e + 3];
    int s4 = colv[e + 4], s5 = colv[e + 5], s6 = colv[e + 6], s7 = colv[e + 7];
    uint2 v0 = G8[(size_t)s0 * 16 + gl];
    uint2 v1 = G8[(size_t)s1 * 16 + gl];
    uint2 v2 = G8[(size_t)s2 * 16 + gl];
    uint2 v3 = G8[(size_t)s3 * 16 + gl];
    uint2 v4 = G8[(size_t)s4 * 16 + gl];
    uint2 v5 = G8[(size_t)s5 * 16 + gl];
    uint2 v6 = G8[(size_t)s6 * 16 + gl];
    uint2 v7 = G8[(size_t)s7 * 16 + gl];
    add8(acc, v0); add8(acc, v1); add8(acc, v2); add8(acc, v3);
    add8(acc, v4); add8(acc, v5); add8(acc, v6); add8(acc, v7);
  }
  for (; e + 4 <= e1; e += 4){
    int s0 = colv[e], s1 = colv[e + 1], s2 = colv[e + 2], s3 = colv[e + 3];
    uint2 v0 = G8[(size_t)s0 * 16 + gl];
    uint2 v1 = G8[(size_t)s1 * 16 + gl];
    uint2 v2 = G8[(size_t)s2 * 16 + gl];
    uint2 v3 = G8[(size_t)s3 * 16 + gl];
    add8(acc, v0); add8(acc, v1); add8(acc, v2); add8(acc, v3);
  }
  for (; e < e1; ++e) add8(acc, G8[(size_t)colv[e] * 16 + gl]);

  float dv = dinv[row];
  float r[8];
  {
    float4 b0 = *(const float4*)(bias + gl * 8);
    float4 b1 = *(const float4*)(bias + gl * 8 + 4);
    r[0] = fmaxf(fmaf(dv, acc[0], b0.x), 0.f);
    r[1] = fmaxf(fmaf(dv, acc[1], b0.y), 0.f);
    r[2] = fmaxf(fmaf(dv, acc[2], b0.z), 0.f);
    r[3] = fmaxf(fmaf(dv, acc[3], b0.w), 0.f);
    r[4] = fmaxf(fmaf(dv, acc[4], b1.x), 0.f);
    r[5] = fmaxf(fmaf(dv, acc[5], b1.y), 0.f);
    r[6] = fmaxf(fmaf(dv, acc[6], b1.z), 0.f);
    r[7] = fmaxf(fmaf(dv, acc[7], b1.w), 0.f);
  }

  if constexpr (!LAST){
    uint2 o;
    o.x = pk4_fp8(r[0], r[1], r[2], r[3]);
    o.y = pk4_fp8(r[4], r[5], r[6], r[7]);
    H[(size_t)row * 16 + gl] = o;               // fp8 row = 128B
  } else {
    float4 w0 = *(const float4*)(W3 + gl * 8);
    float4 w1 = *(const float4*)(W3 + gl * 8 + 4);
    float s = r[0]*w0.x + r[1]*w0.y + r[2]*w0.z + r[3]*w0.w
            + r[4]*w1.x + r[5]*w1.y + r[6]*w1.z + r[7]*w1.w;
    s += __shfl_xor(s, 1); s += __shfl_xor(s, 2);
    s += __shfl_xor(s, 4); s += __shfl_xor(s, 8);
    if (gl == 0) tvec[row] = dv * s;
  }
}

// ---------------- layer 3 final ----------------

__global__ __launch_bounds__(256) void k_final3(const float* __restrict__ tvec, const int* __restrict__ rowptr,
    const int* __restrict__ colv, const float* __restrict__ dinv, const float* __restrict__ b3,
    const float* __restrict__ x, float* __restrict__ out, int n)
{
  int tid = blockIdx.x * 256 + threadIdx.x;
  int row = tid >> 4;
  int gl  = tid & 15;
  if (row >= n) return;
  float s = 0.f;
  int e0 = rowptr[row], e1 = rowptr[row + 1];
  for (int e = e0 + gl; e < e1; e += 16) s += tvec[colv[e]];
  s += __shfl_xor(s, 1); s += __shfl_xor(s, 2);
  s += __shfl_xor(s, 4); s += __shfl_xor(s, 8);
  if (gl == 0){
    s += tvec[row];
    float v = fmaxf(fmaf(dinv[row], s, b3[0]), 0.f);
    out[row] = v + x[(size_t)row * 128 + 127];
  }
}

// ---------------- launch ----------------

extern "C" void kernel_launch(void* const* d_in, const int* in_sizes, int n_in,
                              void* d_out, int out_size, void* d_ws, size_t ws_size,
                              hipStream_t stream)
{
  const float* x  = (const float*)d_in[0];
  const int*   ei = (const int*)d_in[1];
  const float* W1 = (const float*)d_in[3];
  const float* b1 = (const float*)d_in[4];
  const float* W2 = (const float*)d_in[5];
  const float* b2 = (const float*)d_in[6];
  const float* W3 = (const float*)d_in[7];
  const float* b3 = (const float*)d_in[8];
  float* out = (float*)d_out;

  const int N = in_sizes[0] / 128;
  const int E = in_sizes[1] / 2;
  const int* src = ei;
  const int* dst = ei + E;
  const int NB = (N + 127) >> 7;

  char* wsb = (char*)d_ws;
  size_t off = 0;
  auto carve = [&](size_t bytes) -> void* {
    void* p = wsb + off;
    off += bytes;
    off = (off + 255) & ~(size_t)255;
    return p;
  };
  float*    dinv   = (float*)carve((size_t)N * 4);
  int*      rowptr = (int*)carve((size_t)(N + 1) * 4);
  int*      colv   = (int*)carve((size_t)E * 4);
  int*      bpos   = (int*)carve((size_t)NB * 4);
  float*    tvec   = (float*)carve((size_t)N * 4);
  unsigned char* G8 = (unsigned char*)carve((size_t)N * 128);  // fp8 N x 128
  unsigned char* H8 = (unsigned char*)carve((size_t)N * 128);  // fp8 N x 128 (layer1 output)
  unsigned* ebuf   = (unsigned*)G8;   // overlay spans G8+H8 (25.6MB >= NB*BCAP*4 = 19.2MB);
                                      // dead before gemm1 writes G8

  hipMemsetAsync(bpos, 0, (size_t)NB * 4, stream);
  k_part  <<<(E + PART_C - 1) / PART_C, 1024, 0, stream>>>(src, dst, bpos, ebuf, E, NB);
  k_bsort <<<NB, 256, 0, stream>>>(ebuf, bpos, rowptr, colv, dinv, N, E, NB);

  // layer 1
  k_gemm_mfma<true ><<<(N + 127) / 128, 512, 0, stream>>>(x, W1, dinv, G8, N);
  k_spmm<false><<<((size_t)N * 16 + 255) / 256, 256, 0, stream>>>((const uint2*)G8, rowptr, colv, dinv, b1, nullptr, (uint2*)H8, nullptr, N);
  // layer 2 (A = fp8 H)
  k_gemm_mfma<false><<<(N + 127) / 128, 512, 0, stream>>>(H8, W2, dinv, G8, N);
  // layer 2 aggregation fused with layer-3 GEMV epilogue
  k_spmm<true ><<<((size_t)N * 16 + 255) / 256, 256, 0, stream>>>((const uint2*)G8, rowptr, colv, dinv, b2, W3, nullptr, tvec, N);
  // layer 3 aggregation + residual
  k_final3<<<((size_t)N * 16 + 255) / 256, 256, 0, stream>>>(tvec, rowptr, colv, dinv, b3, x, out, N);
}